// Round 3
// baseline (7426.796 us; speedup 1.0000x reference)
//
#include <hip/hip_runtime.h>
#include <cstdint>
#include <cstddef>

#define H      128
#define IN_    12
#define GATES  512   // 4*H
#define B_     256
#define T_     2048
#define TCMAX  512
#define TS     32    // layer-1 gx batch

#define REP32(M) M(0) M(1) M(2) M(3) M(4) M(5) M(6) M(7) M(8) M(9) M(10) M(11) \
  M(12) M(13) M(14) M(15) M(16) M(17) M(18) M(19) M(20) M(21) M(22) M(23) \
  M(24) M(25) M(26) M(27) M(28) M(29) M(30) M(31)

// broadcast one lane's float to all lanes via SGPR (VALU pipe, not DS pipe)
#define RLF(v, l) __int_as_float(__builtin_amdgcn_readlane(__float_as_int(v), (l)))

// recurrent matvec quad: h[4j..4j+3] via readlane from the wave's h copy
// (hl.x = h[2*lane], hl.y = h[2*lane+1]); weights w##j are named float4 regs.
#define QUAD(j) { \
    float s0 = RLF(hl.x, 2*j), s1 = RLF(hl.y, 2*j); \
    float s2 = RLF(hl.x, 2*j+1), s3 = RLF(hl.y, 2*j+1); \
    a0 = fmaf(w##j.x, s0, a0); a1 = fmaf(w##j.y, s1, a1); \
    a2 = fmaf(w##j.z, s2, a2); a3 = fmaf(w##j.w, s3, a3); }

__device__ __forceinline__ float sigmoidf_(float x) {
    return 1.f / (1.f + __expf(-x));
}
__device__ __forceinline__ float tanhf_(float x) {
    return 2.f / (1.f + __expf(-2.f * x)) - 1.f;
}

// ---------------- Layer 0 scan over one chunk ----------------
// 512 threads = 8 waves; thread g owns gate row g. W_hh row in 32 NAMED
// float4 (SSA -> guaranteed VGPRs; the round-1/2 float wh[128] array stayed
// an alloca in scratch, VGPR_Count=112). h broadcast via readlane->SGPR
// instead of wave-uniform ds_read_b128 (DS pipe was the ~1800 cyc/step wall).
__global__ __launch_bounds__(512)
__attribute__((amdgpu_waves_per_eu(2, 2)))
void lstm_l0(const float* __restrict__ x, const float* __restrict__ Wih,
             const float* __restrict__ Whh, const float* __restrict__ bih,
             const float* __restrict__ bhh, float* __restrict__ hs0,
             float* __restrict__ state, int tc, int chunk)
{
    const int b = blockIdx.x;
    const int g = threadIdx.x;
    const int lane = g & 63;

    __shared__ alignas(16) float sh_x[TCMAX * IN_];  // 24 KB
    __shared__ alignas(8)  float sh_h[H];
    __shared__ float sh_act[GATES];

#define LW(j) float4 w##j = ((const float4*)(Whh + (size_t)g * H))[j];
    REP32(LW)
#undef LW
    const float4* wr2 = (const float4*)(Wih + (size_t)g * IN_);
    float4 wiA = wr2[0], wiB = wr2[1], wiC = wr2[2];
    const float bias = bih[g] + bhh[g];

    const float* xs = x + ((size_t)b * T_ + (size_t)chunk * tc) * IN_;
    for (int i = g; i < tc * IN_; i += 512) sh_x[i] = xs[i];

    float hreg = 0.f, creg = 0.f;
    if (g < H) {
        if (chunk) { hreg = state[b * 2 * H + g]; creg = state[b * 2 * H + H + g]; }
        sh_h[g] = hreg;
    }
    __syncthreads();

    float* hs_out = hs0 + (size_t)b * tc * H;

    for (int t = 0; t < tc; ++t) {
        float2 hl = ((const float2*)sh_h)[lane];   // one ds_read_b64/wave
        float a0 = bias, a1 = 0.f, a2 = 0.f, a3 = 0.f;
        const float4* xh = (const float4*)(sh_x + t * IN_);
        float4 xv0 = xh[0], xv1 = xh[1], xv2 = xh[2];
        a0 = fmaf(wiA.x, xv0.x, a0); a1 = fmaf(wiA.y, xv0.y, a1);
        a2 = fmaf(wiA.z, xv0.z, a2); a3 = fmaf(wiA.w, xv0.w, a3);
        a0 = fmaf(wiB.x, xv1.x, a0); a1 = fmaf(wiB.y, xv1.y, a1);
        a2 = fmaf(wiB.z, xv1.z, a2); a3 = fmaf(wiB.w, xv1.w, a3);
        a0 = fmaf(wiC.x, xv2.x, a0); a1 = fmaf(wiC.y, xv2.y, a1);
        a2 = fmaf(wiC.z, xv2.z, a2); a3 = fmaf(wiC.w, xv2.w, a3);
        REP32(QUAD)
        float pre = (a0 + a1) + (a2 + a3);
        float act = ((g >> 7) == 2) ? tanhf_(pre) : sigmoidf_(pre);
        sh_act[g] = act;
        __syncthreads();
        if (g < H) {
            creg = fmaf(sh_act[H + g], creg, sh_act[g] * sh_act[2 * H + g]);
            hreg = sh_act[3 * H + g] * tanhf_(creg);
            sh_h[g] = hreg;
            hs_out[(size_t)t * H + g] = hreg;
        }
        __syncthreads();
    }
    if (g < H) { state[b * 2 * H + g] = hreg; state[b * 2 * H + H + g] = creg; }
}

// ---------------- Layer 1 scan over one chunk ----------------
__global__ __launch_bounds__(512)
__attribute__((amdgpu_waves_per_eu(2, 2)))
void lstm_l1(const float* __restrict__ hs0, const float* __restrict__ Wih,
             const float* __restrict__ Whh, const float* __restrict__ bih,
             const float* __restrict__ bhh, float* __restrict__ state,
             int tc, int chunk)
{
    const int b = blockIdx.x;
    const int g = threadIdx.x;
    const int lane = g & 63;

    __shared__ float sh_gx[TS * GATES];              // 64 KB (same-thread rt)
    __shared__ alignas(8) float sh_h[H];
    __shared__ float sh_act[GATES];

#define LW(j) float4 w##j = ((const float4*)(Whh + (size_t)g * H))[j];
    REP32(LW)
#undef LW
    const float bias = bih[g] + bhh[g];

    float hreg = 0.f, creg = 0.f;
    if (g < H) {
        if (chunk) { hreg = state[b * 2 * H + g]; creg = state[b * 2 * H + H + g]; }
        sh_h[g] = hreg;
    }
    __syncthreads();

    const float* hsrc = hs0 + (size_t)b * tc * H;
    const float4* wihrow = (const float4*)(Wih + (size_t)g * H);

    for (int s = 0; s < tc / TS; ++s) {
        const float* hsA = hsrc + (size_t)s * TS * H;

        // ---- phase A: gx for 32 steps. h0 tile lane-distributed in 32
        // named regs (k = lane in each 64-half); W_ih streamed k-outer from
        // L2; broadcast via readlane with runtime (SGPR) lane index. ----
#define DECL(t) float dA##t;
        REP32(DECL)
#undef DECL
#define ACC(t) float ac##t = bias;
        REP32(ACC)
#undef ACC
#define LTA(t) dA##t = hsA[t * H + lane];
        REP32(LTA)
#undef LTA
        for (int k4 = 0; k4 < 16; ++k4) {
            float4 wq = wihrow[k4];
            int kl = 4 * k4;
#define PA(t) { ac##t = fmaf(wq.x, RLF(dA##t, kl),     ac##t); \
                ac##t = fmaf(wq.y, RLF(dA##t, kl + 1), ac##t); \
                ac##t = fmaf(wq.z, RLF(dA##t, kl + 2), ac##t); \
                ac##t = fmaf(wq.w, RLF(dA##t, kl + 3), ac##t); }
            REP32(PA)
#undef PA
        }
#define LTB(t) dA##t = hsA[t * H + 64 + lane];
        REP32(LTB)
#undef LTB
        for (int k4 = 16; k4 < 32; ++k4) {
            float4 wq = wihrow[k4];
            int kl = 4 * k4 - 64;
#define PB(t) { ac##t = fmaf(wq.x, RLF(dA##t, kl),     ac##t); \
                ac##t = fmaf(wq.y, RLF(dA##t, kl + 1), ac##t); \
                ac##t = fmaf(wq.z, RLF(dA##t, kl + 2), ac##t); \
                ac##t = fmaf(wq.w, RLF(dA##t, kl + 3), ac##t); }
            REP32(PB)
#undef PB
        }
        // park gx in LDS (written and read by the SAME thread -> no barrier)
#define ST(t) sh_gx[t * GATES + g] = ac##t;
        REP32(ST)
#undef ST

        // ---- phase B: 32 sequential recurrent steps ----
        for (int t = 0; t < TS; ++t) {
            float2 hl = ((const float2*)sh_h)[lane];
            float a0 = sh_gx[t * GATES + g], a1 = 0.f, a2 = 0.f, a3 = 0.f;
            REP32(QUAD)
            float pre = (a0 + a1) + (a2 + a3);
            float act = ((g >> 7) == 2) ? tanhf_(pre) : sigmoidf_(pre);
            sh_act[g] = act;
            __syncthreads();
            if (g < H) {
                creg = fmaf(sh_act[H + g], creg, sh_act[g] * sh_act[2 * H + g]);
                hreg = sh_act[3 * H + g] * tanhf_(creg);
                sh_h[g] = hreg;
            }
            __syncthreads();
        }
    }
    if (g < H) { state[b * 2 * H + g] = hreg; state[b * 2 * H + H + g] = creg; }
}

// ---------------- Output projection ----------------
__global__ void out_proj(const float* __restrict__ state1,
                         const float* __restrict__ Wout,
                         const float* __restrict__ bout,
                         float* __restrict__ out)
{
    const int b = blockIdx.x, j = threadIdx.x;
    __shared__ float sh[H];
    if (j < H) sh[j] = state1[b * 2 * H + j];
    __syncthreads();
    if (j < 4) {
        float a = bout[j];
        for (int k = 0; k < H; ++k) a = fmaf(Wout[j * H + k], sh[k], a);
        out[b * 4 + j] = a;
    }
}

extern "C" void kernel_launch(void* const* d_in, const int* in_sizes, int n_in,
                              void* d_out, int out_size, void* d_ws, size_t ws_size,
                              hipStream_t stream)
{
    const float* x    = (const float*)d_in[0];
    const float* Wih0 = (const float*)d_in[1];
    const float* Whh0 = (const float*)d_in[2];
    const float* bih0 = (const float*)d_in[3];
    const float* bhh0 = (const float*)d_in[4];
    const float* Wih1 = (const float*)d_in[5];
    const float* Whh1 = (const float*)d_in[6];
    const float* bih1 = (const float*)d_in[7];
    const float* bhh1 = (const float*)d_in[8];
    const float* Wout = (const float*)d_in[9];
    const float* bout = (const float*)d_in[10];

    // largest chunk that fits the workspace
    int tc = 32;
    for (int cand = TCMAX; cand >= 32; cand >>= 1) {
        size_t need = (size_t)B_ * cand * H * 4 + (size_t)B_ * 2 * H * 4 * 2;
        if (need <= ws_size) { tc = cand; break; }
    }

    float* ws  = (float*)d_ws;
    float* hs0 = ws;                              // B_*tc*H
    float* st0 = ws + (size_t)B_ * tc * H;        // B_*2*H
    float* st1 = st0 + (size_t)B_ * 2 * H;        // B_*2*H

    const int nchunks = T_ / tc;
    for (int c = 0; c < nchunks; ++c) {
        lstm_l0<<<B_, 512, 0, stream>>>(x, Wih0, Whh0, bih0, bhh0, hs0, st0, tc, c);
        lstm_l1<<<B_, 512, 0, stream>>>(hs0, Wih1, Whh1, bih1, bhh1, st1, tc, c);
    }
    out_proj<<<B_, 128, 0, stream>>>(st1, Wout, bout, (float*)d_out);
}

// Round 4
// 5247.175 us; speedup vs baseline: 1.4154x; 1.4154x over previous
//
#include <hip/hip_runtime.h>
#include <cstdint>
#include <cstddef>

#define H      128
#define IN_    12
#define GATES  512   // 4*H
#define B_     256
#define T_     2048
#define TCMAX  512
#define TI     32    // gemm time-tile
#define PS     520   // sh_part ks-stride (512 rows + pad)

#define REP32(M) M(0) M(1) M(2) M(3) M(4) M(5) M(6) M(7) M(8) M(9) M(10) M(11) \
  M(12) M(13) M(14) M(15) M(16) M(17) M(18) M(19) M(20) M(21) M(22) M(23) \
  M(24) M(25) M(26) M(27) M(28) M(29) M(30) M(31)

__device__ __forceinline__ float sigmoidf_(float x) {
    return 1.f / (1.f + __expf(-x));
}
__device__ __forceinline__ float tanhf_(float x) {
    return 2.f / (1.f + __expf(-2.f * x)) - 1.f;
}
__device__ __forceinline__ float dot4f(float4 w, float4 h, float a) {
    return fmaf(w.x, h.x, fmaf(w.y, h.y, fmaf(w.z, h.z, fmaf(w.w, h.w, a))));
}

// ======================= LSTM scan (both layers) =======================
// 1024 threads = 16 waves. thread -> (ks = tid>>7 in [0,8), q = tid&127):
// owns rows 4q..4q+3, k-window [16ks,16ks+16) -> 16 float4 weights = 64 VGPR.
// At 16 waves HW caps 128 VGPR/lane; live pressure ~110 -> true residency
// (512-thr designs pinned VGPR_Count=112 and shuffled weights via AGPR).
// Per step: phase1 all-waves partial dot -> sh_part[ks][i*128+q] (stride-1
// lanes, conflict-free); barrier; phase2 (tid<128) reduce 32 partials +
// activations + c/h update; barrier.
// L0: x-proj folded into ks 1..3 partials from sh_x. L1: gx preloaded from
// global with one-step register prefetch (bias already folded by gemm).
template<bool IS_L0>
__global__ __launch_bounds__(1024) void lstm_scan(
    const float* __restrict__ x_or_gx,   // L0: x [B,T,12]; L1: gx chunk [B,tc,512]
    const float* __restrict__ Wih,       // L0 only [512,12]
    const float* __restrict__ Whh,       // [512,128]
    const float* __restrict__ bih, const float* __restrict__ bhh, // L0 only
    float* __restrict__ hs0,             // L0: out [B,tc,128]; L1: unused
    float* __restrict__ state,           // [B,2,128]
    int tc, int chunk)
{
    const int b   = blockIdx.x;
    const int tid = threadIdx.x;
    const int ks  = tid >> 7;    // 0..7
    const int q   = tid & 127;   // row quad

    extern __shared__ float smem[];
    float* sh_part = smem;                  // 8*PS
    float* sh_h    = smem + 8 * PS;         // 128
    float* sh_x    = sh_h + H;              // L0: tc*12

    // resident W_hh fragment: rows 4q..4q+3, cols 16ks..16ks+15
#define LOADW(i) \
    const float4* wr##i = (const float4*)(Whh + (size_t)(4*q+i)*H + 16*ks); \
    float4 w##i##0 = wr##i[0], w##i##1 = wr##i[1], w##i##2 = wr##i[2], w##i##3 = wr##i[3];
    LOADW(0) LOADW(1) LOADW(2) LOADW(3)
#undef LOADW

    // L0: x-proj weights for ks 1..3 (4 floats per row)
    float4 wx0 = {0,0,0,0}, wx1 = {0,0,0,0}, wx2 = {0,0,0,0}, wx3 = {0,0,0,0};
    if constexpr (IS_L0) {
        if (ks >= 1 && ks <= 3) {
            wx0 = *(const float4*)(Wih + (size_t)(4*q+0)*IN_ + 4*(ks-1));
            wx1 = *(const float4*)(Wih + (size_t)(4*q+1)*IN_ + 4*(ks-1));
            wx2 = *(const float4*)(Wih + (size_t)(4*q+2)*IN_ + 4*(ks-1));
            wx3 = *(const float4*)(Wih + (size_t)(4*q+3)*IN_ + 4*(ks-1));
        }
        // stage x chunk
        const float* xs = x_or_gx + ((size_t)b * T_ + (size_t)chunk * tc) * IN_;
        for (int i = tid; i < tc * IN_; i += 1024) sh_x[i] = xs[i];
    }

    // epilogue-thread state (tid<128): biases, h/c, gx prefetch regs
    float bias0 = 0, bias1 = 0, bias2 = 0, bias3 = 0;
    float cur0 = 0, cur1 = 0, cur2 = 0, cur3 = 0;
    float hreg = 0.f, creg = 0.f;
    const float* gxb = nullptr;
    if constexpr (!IS_L0) gxb = x_or_gx + (size_t)b * tc * GATES;

    if (tid < H) {
        if constexpr (IS_L0) {
            bias0 = bih[tid]         + bhh[tid];
            bias1 = bih[tid + 128]   + bhh[tid + 128];
            bias2 = bih[tid + 256]   + bhh[tid + 256];
            bias3 = bih[tid + 384]   + bhh[tid + 384];
        } else {
            cur0 = gxb[tid]; cur1 = gxb[tid + 128];
            cur2 = gxb[tid + 256]; cur3 = gxb[tid + 384];
        }
        if (chunk) { hreg = state[b*2*H + tid]; creg = state[b*2*H + H + tid]; }
        sh_h[tid] = hreg;
    }
    __syncthreads();

    float* hs_out = nullptr;
    if constexpr (IS_L0) hs_out = hs0 + (size_t)b * tc * H;

    const float4* sh4 = (const float4*)sh_h;
    const int i0 = tid & 3, q0 = tid >> 2;   // phase-2 partial coords

    for (int t = 0; t < tc; ++t) {
        // ---- phase 1: partial dots (all 16 waves) ----
        float n0 = 0, n1 = 0, n2 = 0, n3 = 0;   // next-step gx prefetch
        if constexpr (!IS_L0) {
            if (tid < H) {
                int tn = (t + 1 < tc) ? t + 1 : t;
                const float* gp = gxb + (size_t)tn * GATES;
                n0 = gp[tid]; n1 = gp[tid + 128];
                n2 = gp[tid + 256]; n3 = gp[tid + 384];
            }
        }
        float4 hA = sh4[4*ks], hB = sh4[4*ks+1], hC = sh4[4*ks+2], hD = sh4[4*ks+3];
        float a0 = dot4f(w03,hD, dot4f(w02,hC, dot4f(w01,hB, dot4f(w00,hA, 0.f))));
        float a1 = dot4f(w13,hD, dot4f(w12,hC, dot4f(w11,hB, dot4f(w10,hA, 0.f))));
        float a2 = dot4f(w23,hD, dot4f(w22,hC, dot4f(w21,hB, dot4f(w20,hA, 0.f))));
        float a3 = dot4f(w33,hD, dot4f(w32,hC, dot4f(w31,hB, dot4f(w30,hA, 0.f))));
        if constexpr (IS_L0) {
            if (ks >= 1 && ks <= 3) {
                float4 xq = *(const float4*)(sh_x + t * IN_ + 4*(ks-1));
                a0 = dot4f(wx0, xq, a0); a1 = dot4f(wx1, xq, a1);
                a2 = dot4f(wx2, xq, a2); a3 = dot4f(wx3, xq, a3);
            }
        }
        sh_part[ks*PS + 0*128 + q] = a0;
        sh_part[ks*PS + 1*128 + q] = a1;
        sh_part[ks*PS + 2*128 + q] = a2;
        sh_part[ks*PS + 3*128 + q] = a3;
        __syncthreads();

        // ---- phase 2: reduce + activate + state update (tid<128) ----
        if (tid < H) {
            float p0, p1, p2, p3;
            {
                const float* pb = sh_part + i0*128 + q0;
#define RSUM(m, dst) { \
                float s = pb[32*m]; \
                s += pb[32*m + 1*PS]; s += pb[32*m + 2*PS]; s += pb[32*m + 3*PS]; \
                s += pb[32*m + 4*PS]; s += pb[32*m + 5*PS]; s += pb[32*m + 6*PS]; \
                s += pb[32*m + 7*PS]; dst = s; }
                RSUM(0, p0) RSUM(1, p1) RSUM(2, p2) RSUM(3, p3)
#undef RSUM
            }
            float gi, gf, gg, go;
            if constexpr (IS_L0) {
                gi = p0 + bias0; gf = p1 + bias1; gg = p2 + bias2; go = p3 + bias3;
            } else {
                gi = p0 + cur0; gf = p1 + cur1; gg = p2 + cur2; go = p3 + cur3;
                cur0 = n0; cur1 = n1; cur2 = n2; cur3 = n3;
            }
            creg = fmaf(sigmoidf_(gf), creg, sigmoidf_(gi) * tanhf_(gg));
            hreg = sigmoidf_(go) * tanhf_(creg);
            sh_h[tid] = hreg;
            if constexpr (IS_L0) hs_out[(size_t)t * H + tid] = hreg;
        }
        __syncthreads();
    }
    if (tid < H) { state[b*2*H + tid] = hreg; state[b*2*H + H + tid] = creg; }
}

// ======================= gx1 GEMM =======================
// gx1[b,t,g] = bias1[g] + sum_k hs0[b,t,k] * Wih1[g,k]
// block = (batch b, 32-step tile); 512 threads, thread = gate g.
// 32 named accumulators (~45 VGPR live); W row streamed k-outer from L2;
// h tile staged in LDS, uniform-broadcast float4 reads.
__global__ __launch_bounds__(512) void gx1_gemm(
    const float* __restrict__ hs0, const float* __restrict__ Wih,
    const float* __restrict__ bih, const float* __restrict__ bhh,
    float* __restrict__ gx, int tc)
{
    const int b  = blockIdx.x;
    const int t0 = blockIdx.y * TI;
    const int g  = threadIdx.x;

    __shared__ alignas(16) float sh_h0[TI * H];   // 16 KB

    const float4* src4 = (const float4*)(hs0 + ((size_t)b * tc + t0) * H);
    float4* dst4 = (float4*)sh_h0;
    for (int i = g; i < TI * H / 4; i += 512) dst4[i] = src4[i];

    const float biasg = bih[g] + bhh[g];
#define AI(t) float acc##t = biasg;
    REP32(AI)
#undef AI
    __syncthreads();

    const float4* wrow = (const float4*)(Wih + (size_t)g * H);
    const float4* sh4h = (const float4*)sh_h0;
    for (int k4 = 0; k4 < H / 4; ++k4) {
        float4 wq = wrow[k4];
#define PA(t) { float4 hv = sh4h[t*32 + k4]; \
        acc##t = fmaf(wq.x, hv.x, fmaf(wq.y, hv.y, fmaf(wq.z, hv.z, fmaf(wq.w, hv.w, acc##t)))); }
        REP32(PA)
#undef PA
    }

    float* gxo = gx + (size_t)b * tc * GATES;
#define SG(t) gxo[(size_t)(t0 + t) * GATES + g] = acc##t;
    REP32(SG)
#undef SG
}

// ======================= output projection =======================
__global__ void out_proj(const float* __restrict__ state1,
                         const float* __restrict__ Wout,
                         const float* __restrict__ bout,
                         float* __restrict__ out)
{
    const int b = blockIdx.x, j = threadIdx.x;
    __shared__ float sh[H];
    if (j < H) sh[j] = state1[b*2*H + j];
    __syncthreads();
    if (j < 4) {
        float a = bout[j];
        for (int k = 0; k < H; ++k) a = fmaf(Wout[j*H + k], sh[k], a);
        out[b*4 + j] = a;
    }
}

extern "C" void kernel_launch(void* const* d_in, const int* in_sizes, int n_in,
                              void* d_out, int out_size, void* d_ws, size_t ws_size,
                              hipStream_t stream)
{
    const float* x    = (const float*)d_in[0];
    const float* Wih0 = (const float*)d_in[1];
    const float* Whh0 = (const float*)d_in[2];
    const float* bih0 = (const float*)d_in[3];
    const float* bhh0 = (const float*)d_in[4];
    const float* Wih1 = (const float*)d_in[5];
    const float* Whh1 = (const float*)d_in[6];
    const float* bih1 = (const float*)d_in[7];
    const float* bhh1 = (const float*)d_in[8];
    const float* Wout = (const float*)d_in[9];
    const float* bout = (const float*)d_in[10];

    // ws layout: st0 | st1 | hs0 chunk | gx1 chunk
    int tc = 32;
    for (int cand = TCMAX; cand >= 32; cand >>= 1) {
        size_t need = (size_t)2 * B_ * 2 * H * 4
                    + (size_t)B_ * cand * H * 4
                    + (size_t)B_ * cand * GATES * 4;
        if (need <= ws_size) { tc = cand; break; }
    }

    float* ws  = (float*)d_ws;
    float* st0 = ws;
    float* st1 = st0 + (size_t)B_ * 2 * H;
    float* hs0 = st1 + (size_t)B_ * 2 * H;
    float* gx1 = hs0 + (size_t)B_ * tc * H;

    const size_t shm_l0 = (size_t)(8 * PS + H + tc * IN_) * 4;
    const size_t shm_l1 = (size_t)(8 * PS + H) * 4;

    const int nchunks = T_ / tc;
    for (int c = 0; c < nchunks; ++c) {
        lstm_scan<true><<<B_, 1024, shm_l0, stream>>>(
            x, Wih0, Whh0, bih0, bhh0, hs0, st0, tc, c);
        gx1_gemm<<<dim3(B_, tc / TI), 512, 0, stream>>>(
            hs0, Wih1, bih1, bhh1, gx1, tc);
        lstm_scan<false><<<B_, 1024, shm_l1, stream>>>(
            gx1, nullptr, Whh1, nullptr, nullptr, nullptr, st1, tc, c);
    }
    out_proj<<<B_, 128, 0, stream>>>(st1, Wout, bout, (float*)d_out);
}